// Round 12
// baseline (507.502 us; speedup 1.0000x reference)
//
#include <hip/hip_runtime.h>

#define E_NUM 8
#define FFN_DIM 8192
#define D_DIM 2048
#define T_DIM 4096

using bf16x8 = __attribute__((ext_vector_type(8))) short;
using f32x4  = __attribute__((ext_vector_type(4))) float;
using u16x8  = __attribute__((ext_vector_type(8))) unsigned short;

__device__ __forceinline__ unsigned short f2bf(float f) {
  union { float f; unsigned int u; } v; v.f = f;
  unsigned int u = v.u;
  unsigned int r = (u + 0x7FFFu + ((u >> 16) & 1u)) >> 16;
  return (unsigned short)r;
}

__device__ __forceinline__ void gload16(const unsigned short* g, const unsigned short* l) {
  __builtin_amdgcn_global_load_lds(
      (const __attribute__((address_space(1))) void*)g,
      (__attribute__((address_space(3))) void*)l, 16, 0, 0);
}

// ---------- prep: fp32 -> bf16 convert ----------
__global__ void convert_kernel(const float* __restrict__ src_base,
                               const int* __restrict__ eidx, long slab,
                               unsigned short* __restrict__ dst, long n) {
  const float* src = src_base + (long)(*eidx) * slab;
  long stride = (long)gridDim.x * blockDim.x;
  for (long i = (long)blockIdx.x * blockDim.x + threadIdx.x; i * 8 < n; i += stride) {
    long e = i * 8;
    const float4* p = (const float4*)(src + e);
    float4 f0 = p[0], f1 = p[1];
    u16x8 o;
    o[0] = f2bf(f0.x); o[1] = f2bf(f0.y); o[2] = f2bf(f0.z); o[3] = f2bf(f0.w);
    o[4] = f2bf(f1.x); o[5] = f2bf(f1.y); o[6] = f2bf(f1.z); o[7] = f2bf(f1.w);
    *(u16x8*)(dst + e) = o;
  }
}

// ---------- prep: transpose w2 (FFN,D) fp32 -> (D,FFN) bf16, 64x64 tiles ----------
__global__ __launch_bounds__(512) void transpose_kernel(
    const float* __restrict__ w2, const int* __restrict__ eidx,
    unsigned short* __restrict__ dst) {
  __shared__ unsigned short tile[64][72];
  const float* src = w2 + (long)(*eidx) * (long)FFN_DIM * D_DIM;
  const int tid = threadIdx.x;
  int d0 = blockIdx.x << 6;
  int f0 = blockIdx.y << 6;
#pragma unroll
  for (int p = 0; p < 2; ++p) {
    int f = p * 32 + (tid >> 4);
    int dc = (tid & 15) * 4;
    float4 v = *(const float4*)(src + (long)(f0 + f) * D_DIM + d0 + dc);
    tile[f][dc + 0] = f2bf(v.x); tile[f][dc + 1] = f2bf(v.y);
    tile[f][dc + 2] = f2bf(v.z); tile[f][dc + 3] = f2bf(v.w);
  }
  __syncthreads();
  int d = tid >> 3;
  int fc = (tid & 7) * 8;
  u16x8 o;
#pragma unroll
  for (int j = 0; j < 8; ++j) o[j] = tile[fc + j][d];
  *(u16x8*)(dst + (long)(d0 + d) * FFN_DIM + f0 + fc) = o;
}

// Counted vmcnt waits, memory-clobbered (stage issues pinned -> count exact).
#define VMCNT6 asm volatile("s_waitcnt vmcnt(6)" ::: "memory")
#define VMCNT5 asm volatile("s_waitcnt vmcnt(5)" ::: "memory")
#define VMCNT0 asm volatile("s_waitcnt vmcnt(0)" ::: "memory")
// m201 phase structure: {reads; stage} BAR1; LGKM0; MFMA; BAR1.
// Each phase's ds_reads drain (LGKM0) before its own MFMA and before its
// trailing barrier => no wave can issue a later-phase stage that overwrites
// rows another wave hasn't sampled. WAR-safe by construction.
#define BAR1  asm volatile("s_barrier" ::: "memory")
#define LGKM0 asm volatile("s_waitcnt lgkmcnt(0)" ::: "memory")
#define LGKM8 asm volatile("s_waitcnt lgkmcnt(8)" ::: "memory")
#define PRIO1 __builtin_amdgcn_s_setprio(1)
#define PRIO0 __builtin_amdgcn_s_setprio(0)

// ---------- GEMM1 fused: m201-style 4-phase, 2 barriers/phase ----------
// tile 256m x 128n(dual), BK=64, 8 waves 2Mx4N, wave 128x32 per GEMM.
// Units (2 loads each): Alo(A r0-127), Ahi(r128-255), B1, B2.
// Reads: P1:{Alo,B1} P2:{Ahi} P3:{B2} P4:{} (ops consumed in-phase).
// Stages: P1:B2(t+1)[nx]  P2:Alo(t+2)[db]  P3:B1(t+2)[db]  P4:Ahi(t+2)[db].
// vmcnt(6)@P4: pre-wait 14 outstanding -> drains the 8 of tile t+1 exactly.
// WAR: every same-dbuf stage lands >=1 barrier after that region's last
// in-phase-drained read (audited per phase).
__global__ __launch_bounds__(512, 2) void gemm1_silu(
    const unsigned short* __restrict__ Xb,    // (4096,2048)
    const unsigned short* __restrict__ W1b,   // (8192,2048)
    const unsigned short* __restrict__ V1b,   // (8192,2048)
    unsigned short* __restrict__ Hb) {        // (4096,8192)
  __shared__ __align__(16) unsigned short sA[2 * 16384];   // [dbuf][256x64]
  __shared__ __align__(16) unsigned short sB1[2 * 8192];   // [dbuf][128x64]
  __shared__ __align__(16) unsigned short sB2[2 * 8192];

  const int tid = threadIdx.x;
  const int wv = tid >> 6, l = tid & 63;
  const int wm = wv >> 2, wn = wv & 3;        // 2M x 4N
  const int kq = l >> 4, lr = l & 15;
  const int bsw = (blockIdx.x & 7) * 128 + (blockIdx.x >> 3);
  const int m0 = (bsw >> 6) << 8;
  const int n0 = (bsw & 63) << 7;

  const int rsub = tid >> 3;
  const int sslot8 = ((tid & 7) ^ ((tid >> 3) & 7)) << 3;
  const unsigned short* gA  = Xb  + (long)(m0 + rsub) * D_DIM + sslot8;
  const unsigned short* gB1 = W1b + (long)(n0 + rsub) * D_DIM + sslot8;
  const unsigned short* gB2 = V1b + (long)(n0 + rsub) * D_DIM + sslot8;

#define STG1(gbase, r_, tc_, lbase) \
  gload16((gbase) + (long)((r_) * 64) * D_DIM + (tc_), (lbase) + (r_) * 4096 + wv * 512)

  int aoffA[4], aoffB[4], boff[2];
#pragma unroll
  for (int j = 0; j < 4; ++j) {
    int rowA = wm * 64 + j * 16 + lr;
    aoffA[j] = rowA * 64 + ((kq ^ (rowA & 7)) << 3);
    int rowB = 128 + wm * 64 + j * 16 + lr;
    aoffB[j] = rowB * 64 + ((kq ^ (rowB & 7)) << 3);
  }
#pragma unroll
  for (int g = 0; g < 2; ++g) {
    int row = wn * 32 + g * 16 + lr;
    boff[g] = row * 64 + ((kq ^ (row & 7)) << 3);
  }

  f32x4 acc1[8][2], acc2[8][2];
  f32x4 z = {0.f, 0.f, 0.f, 0.f};
#pragma unroll
  for (int f = 0; f < 8; ++f)
#pragma unroll
    for (int g = 0; g < 2; ++g) { acc1[f][g] = z; acc2[f][g] = z; }

  bf16x8 aA[4][2], aB[4][2], b1[2][2], b2[2][2];

  // prologue: tile0 {Alo,B1,Ahi,B2} + tile1 {Alo,B1,Ahi} = 14 loads;
  // vmcnt(6) drains tile0's 8, leaving the steady-state 6. NO pre-reads.
  STG1(gA, 0, 0, sA); STG1(gA, 1, 0, sA);
  STG1(gB1, 0, 0, sB1); STG1(gB1, 1, 0, sB1);
  STG1(gA, 2, 0, sA); STG1(gA, 3, 0, sA);
  STG1(gB2, 0, 0, sB2); STG1(gB2, 1, 0, sB2);
  STG1(gA, 0, 64, sA + 16384); STG1(gA, 1, 64, sA + 16384);
  STG1(gB1, 0, 64, sB1 + 8192); STG1(gB1, 1, 64, sB1 + 8192);
  STG1(gA, 2, 64, sA + 16384); STG1(gA, 3, 64, sA + 16384);
  VMCNT6;
  BAR1;

  const int NT = D_DIM / 64;  // 32
  for (int t = 0; t < NT; ++t) {
    const int db = t & 1, nx = db ^ 1;
    const unsigned short* Acur  = sA  + db * 16384;
    const unsigned short* B1cur = sB1 + db * 8192;
    const unsigned short* B2cur = sB2 + db * 8192;
    unsigned short* AdbW  = (unsigned short*)sA  + db * 16384;
    unsigned short* B1dbW = (unsigned short*)sB1 + db * 8192;
    unsigned short* B2nxW = (unsigned short*)sB2 + nx * 8192;
    const int p1ok = (t + 1 < NT), p2ok = (t + 2 < NT);
    const int tc1 = (t + 1) << 6, tc2 = (t + 2) << 6;

    // ---- P1: read Alo+B1; stage B2(t+1)[nx]; MFMA acc1-lo ----
#pragma unroll
    for (int j = 0; j < 4; ++j) {
      aA[j][0] = *(const bf16x8*)(Acur + aoffA[j]);
      aA[j][1] = *(const bf16x8*)(Acur + (aoffA[j] ^ 32));
    }
#pragma unroll
    for (int g = 0; g < 2; ++g) {
      b1[g][0] = *(const bf16x8*)(B1cur + boff[g]);
      b1[g][1] = *(const bf16x8*)(B1cur + (boff[g] ^ 32));
    }
    if (p1ok) { STG1(gB2, 0, tc1, B2nxW); STG1(gB2, 1, tc1, B2nxW); }
    LGKM8;
    BAR1;
    LGKM0;
    PRIO1;
#pragma unroll
    for (int j = 0; j < 4; ++j)
#pragma unroll
      for (int g = 0; g < 2; ++g) {
        acc1[j][g] = __builtin_amdgcn_mfma_f32_16x16x32_bf16(aA[j][0], b1[g][0], acc1[j][g], 0, 0, 0);
        acc1[j][g] = __builtin_amdgcn_mfma_f32_16x16x32_bf16(aA[j][1], b1[g][1], acc1[j][g], 0, 0, 0);
      }
    PRIO0;
    BAR1;

    // ---- P2: read Ahi; stage Alo(t+2)[db]; MFMA acc1-hi ----
#pragma unroll
    for (int j = 0; j < 4; ++j) {
      aB[j][0] = *(const bf16x8*)(Acur + aoffB[j]);
      aB[j][1] = *(const bf16x8*)(Acur + (aoffB[j] ^ 32));
    }
    if (p2ok) { STG1(gA, 0, tc2, AdbW); STG1(gA, 1, tc2, AdbW); }
    BAR1;
    LGKM0;
    PRIO1;
#pragma unroll
    for (int j = 0; j < 4; ++j)
#pragma unroll
      for (int g = 0; g < 2; ++g) {
        acc1[4 + j][g] = __builtin_amdgcn_mfma_f32_16x16x32_bf16(aB[j][0], b1[g][0], acc1[4 + j][g], 0, 0, 0);
        acc1[4 + j][g] = __builtin_amdgcn_mfma_f32_16x16x32_bf16(aB[j][1], b1[g][1], acc1[4 + j][g], 0, 0, 0);
      }
    PRIO0;
    BAR1;

    // ---- P3: read B2; stage B1(t+2)[db]; MFMA acc2-lo ----
#pragma unroll
    for (int g = 0; g < 2; ++g) {
      b2[g][0] = *(const bf16x8*)(B2cur + boff[g]);
      b2[g][1] = *(const bf16x8*)(B2cur + (boff[g] ^ 32));
    }
    if (p2ok) { STG1(gB1, 0, tc2, B1dbW); STG1(gB1, 1, tc2, B1dbW); }
    BAR1;
    LGKM0;
    PRIO1;
#pragma unroll
    for (int j = 0; j < 4; ++j)
#pragma unroll
      for (int g = 0; g < 2; ++g) {
        acc2[j][g] = __builtin_amdgcn_mfma_f32_16x16x32_bf16(aA[j][0], b2[g][0], acc2[j][g], 0, 0, 0);
        acc2[j][g] = __builtin_amdgcn_mfma_f32_16x16x32_bf16(aA[j][1], b2[g][1], acc2[j][g], 0, 0, 0);
      }
    PRIO0;
    BAR1;

    // ---- P4: stage Ahi(t+2)[db]; MFMA acc2-hi; vmcnt(6) ----
    if (p2ok) { STG1(gA, 2, tc2, AdbW); STG1(gA, 3, tc2, AdbW); }
    BAR1;
    PRIO1;
#pragma unroll
    for (int j = 0; j < 4; ++j)
#pragma unroll
      for (int g = 0; g < 2; ++g) {
        acc2[4 + j][g] = __builtin_amdgcn_mfma_f32_16x16x32_bf16(aB[j][0], b2[g][0], acc2[4 + j][g], 0, 0, 0);
        acc2[4 + j][g] = __builtin_amdgcn_mfma_f32_16x16x32_bf16(aB[j][1], b2[g][1], acc2[4 + j][g], 0, 0, 0);
      }
    PRIO0;
    if (p2ok) { VMCNT6; } else if (p1ok) { VMCNT0; }
    BAR1;
  }

  // epilogue: h = silu(x1)*x2, bf16
#pragma unroll
  for (int f = 0; f < 8; ++f)
#pragma unroll
    for (int g = 0; g < 2; ++g)
#pragma unroll
      for (int r = 0; r < 4; ++r) {
        int row = m0 + (f >> 2) * 128 + wm * 64 + (f & 3) * 16 + kq * 4 + r;
        int col = n0 + wn * 32 + g * 16 + lr;
        float x1 = acc1[f][g][r], x2 = acc2[f][g][r];
        float hv = x1 / (1.f + __expf(-x1)) * x2;
        Hb[(long)row * FFN_DIM + col] = f2bf(hv);
      }
#undef STG1
}

// ---------- GEMM2: m201-style 4-phase, 2 barriers/phase ----------
// tile 256m x 128n, BK=64, 8 waves 4Mx2N, wave 64x64.
// Units (loads): Alo=2, Ahi=2, Blo=1, Bhi=1. Reads: P1:{f01,g01} P2:{f23}
// P3:{g23} P4:{}. A halves read P1+P2; B halves read P1+P3 => same-dbuf
// stages legal only: A@P3/P4, B@P4. Map: P1:Bhi(t+1)[nx]; P3:Alo(t+2)[db];
// P4:Ahi(t+2)+Blo(t+2)[db]. vmcnt(5)@P4: pre-wait 11 -> drains t+1's 6.
__global__ __launch_bounds__(512, 2) void gemm2(
    const unsigned short* __restrict__ Hb,    // (4096,8192)
    const unsigned short* __restrict__ W2T,   // (2048,8192)
    float* __restrict__ out) {                // (4096,2048)
  __shared__ __align__(16) unsigned short sA[2 * 16384];
  __shared__ __align__(16) unsigned short sB[2 * 8192];

  const int tid = threadIdx.x;
  const int wv = tid >> 6, l = tid & 63;
  const int wm = wv >> 1, wn = wv & 1;        // 4M x 2N
  const int kq = l >> 4, lr = l & 15;
  const int bsw = (blockIdx.x & 7) * 32 + (blockIdx.x >> 3);
  const int m0 = (bsw >> 4) << 8;
  const int n0 = (bsw & 15) << 7;

  const int rsub = tid >> 3;
  const int sslot8 = ((tid & 7) ^ ((tid >> 3) & 7)) << 3;
  const unsigned short* gA = Hb  + (long)(m0 + rsub) * FFN_DIM + sslot8;
  const unsigned short* gB = W2T + (long)(n0 + rsub) * FFN_DIM + sslot8;

#define STG1(gbase, r_, tc_, lbase) \
  gload16((gbase) + (long)((r_) * 64) * FFN_DIM + (tc_), (lbase) + (r_) * 4096 + wv * 512)

  int aoff[4], boff[4];
#pragma unroll
  for (int f = 0; f < 4; ++f) {
    int row = wm * 64 + f * 16 + lr;
    aoff[f] = row * 64 + ((kq ^ (row & 7)) << 3);
  }
#pragma unroll
  for (int g = 0; g < 4; ++g) {
    int row = wn * 64 + g * 16 + lr;
    boff[g] = row * 64 + ((kq ^ (row & 7)) << 3);
  }

  f32x4 acc[4][4];
  f32x4 z = {0.f, 0.f, 0.f, 0.f};
#pragma unroll
  for (int f = 0; f < 4; ++f)
#pragma unroll
    for (int g = 0; g < 4; ++g) acc[f][g] = z;

  bf16x8 aA[2][2], aB[2][2], bA[2][2], bB[2][2];

  // prologue: tile0 (6 loads) + tile1 {Alo,Ahi,Blo} (5) = 11; vmcnt(5)
  // drains tile0's 6. No pre-reads.
  STG1(gA, 0, 0, sA); STG1(gA, 1, 0, sA);
  STG1(gA, 2, 0, sA); STG1(gA, 3, 0, sA);
  STG1(gB, 0, 0, sB); STG1(gB, 1, 0, sB);
  STG1(gA, 0, 64, sA + 16384); STG1(gA, 1, 64, sA + 16384);
  STG1(gA, 2, 64, sA + 16384); STG1(gA, 3, 64, sA + 16384);
  STG1(gB, 0, 64, sB + 8192);
  VMCNT5;
  BAR1;

  const int NT = FFN_DIM / 64;  // 128
  for (int t = 0; t < NT; ++t) {
    const int db = t & 1, nx = db ^ 1;
    const unsigned short* Acur = sA + db * 16384;
    const unsigned short* Bcur = sB + db * 8192;
    unsigned short* AdbW = (unsigned short*)sA + db * 16384;
    unsigned short* BdbW = (unsigned short*)sB + db * 8192;
    unsigned short* BnxW = (unsigned short*)sB + nx * 8192;
    const int p1ok = (t + 1 < NT), p2ok = (t + 2 < NT);
    const int tc1 = (t + 1) << 6, tc2 = (t + 2) << 6;

    // ---- P1: read f01+g01; stage Bhi(t+1)[nx]; MFMA f01xg01 ----
#pragma unroll
    for (int f = 0; f < 2; ++f) {
      aA[f][0] = *(const bf16x8*)(Acur + aoff[f]);
      aA[f][1] = *(const bf16x8*)(Acur + (aoff[f] ^ 32));
    }
#pragma unroll
    for (int g = 0; g < 2; ++g) {
      bA[g][0] = *(const bf16x8*)(Bcur + boff[g]);
      bA[g][1] = *(const bf16x8*)(Bcur + (boff[g] ^ 32));
    }
    if (p1ok) { STG1(gB, 1, tc1, BnxW); }
    BAR1;
    LGKM0;
    PRIO1;
#pragma unroll
    for (int f = 0; f < 2; ++f)
#pragma unroll
      for (int g = 0; g < 2; ++g) {
        acc[f][g] = __builtin_amdgcn_mfma_f32_16x16x32_bf16(aA[f][0], bA[g][0], acc[f][g], 0, 0, 0);
        acc[f][g] = __builtin_amdgcn_mfma_f32_16x16x32_bf16(aA[f][1], bA[g][1], acc[f][g], 0, 0, 0);
      }
    PRIO0;
    BAR1;

    // ---- P2: read f23; MFMA f23xg01 ----
#pragma unroll
    for (int f = 0; f < 2; ++f) {
      aB[f][0] = *(const bf16x8*)(Acur + aoff[2 + f]);
      aB[f][1] = *(const bf16x8*)(Acur + (aoff[2 + f] ^ 32));
    }
    BAR1;
    LGKM0;
    PRIO1;
#pragma unroll
    for (int f = 0; f < 2; ++f)
#pragma unroll
      for (int g = 0; g < 2; ++g) {
        acc[2 + f][g] = __builtin_amdgcn_mfma_f32_16x16x32_bf16(aB[f][0], bA[g][0], acc[2 + f][g], 0, 0, 0);
        acc[2 + f][g] = __builtin_amdgcn_mfma_f32_16x16x32_bf16(aB[f][1], bA[g][1], acc[2 + f][g], 0, 0, 0);
      }
    PRIO0;
    BAR1;

    // ---- P3: read g23; stage Alo(t+2)[db]; MFMA f01xg23 ----
#pragma unroll
    for (int g = 0; g < 2; ++g) {
      bB[g][0] = *(const bf16x8*)(Bcur + boff[2 + g]);
      bB[g][1] = *(const bf16x8*)(Bcur + (boff[2 + g] ^ 32));
    }
    if (p2ok) { STG1(gA, 0, tc2, AdbW); STG1(gA, 1, tc2, AdbW); }
    BAR1;
    LGKM0;
    PRIO1;
#pragma unroll
    for (int f = 0; f < 2; ++f)
#pragma unroll
      for (int g = 0; g < 2; ++g) {
        acc[f][2 + g] = __builtin_amdgcn_mfma_f32_16x16x32_bf16(aA[f][0], bB[g][0], acc[f][2 + g], 0, 0, 0);
        acc[f][2 + g] = __builtin_amdgcn_mfma_f32_16x16x32_bf16(aA[f][1], bB[g][1], acc[f][2 + g], 0, 0, 0);
      }
    PRIO0;
    BAR1;

    // ---- P4: stage Ahi(t+2)+Blo(t+2)[db]; MFMA f23xg23; vmcnt(5) ----
    if (p2ok) { STG1(gA, 2, tc2, AdbW); STG1(gA, 3, tc2, AdbW); STG1(gB, 0, tc2, BdbW); }
    BAR1;
    PRIO1;
#pragma unroll
    for (int f = 0; f < 2; ++f)
#pragma unroll
      for (int g = 0; g < 2; ++g) {
        acc[2 + f][2 + g] = __builtin_amdgcn_mfma_f32_16x16x32_bf16(aB[f][0], bB[g][0], acc[2 + f][2 + g], 0, 0, 0);
        acc[2 + f][2 + g] = __builtin_amdgcn_mfma_f32_16x16x32_bf16(aB[f][1], bB[g][1], acc[2 + f][2 + g], 0, 0, 0);
      }
    PRIO0;
    if (p2ok) { VMCNT5; } else if (p1ok) { VMCNT0; }
    BAR1;
  }

#pragma unroll
  for (int f = 0; f < 4; ++f)
#pragma unroll
    for (int g = 0; g < 4; ++g)
#pragma unroll
      for (int r = 0; r < 4; ++r) {
        int row = m0 + wm * 64 + f * 16 + kq * 4 + r;
        int col = n0 + wn * 64 + g * 16 + lr;
        out[(long)row * D_DIM + col] = acc[f][g][r];
      }
#undef STG1
}

extern "C" void kernel_launch(void* const* d_in, const int* in_sizes, int n_in,
                              void* d_out, int out_size, void* d_ws, size_t ws_size,
                              hipStream_t stream) {
  const float* x  = (const float*)d_in[0];
  const float* w1 = (const float*)d_in[1];
  const float* v1 = (const float*)d_in[2];
  const float* w2 = (const float*)d_in[3];
  const int* eidx = (const int*)d_in[4];

  char* ws = (char*)d_ws;
  unsigned short* Xb  = (unsigned short*)(ws);                  // 16 MiB
  unsigned short* W1b = (unsigned short*)(ws + (16l << 20));    // 32 MiB
  unsigned short* V1b = (unsigned short*)(ws + (48l << 20));    // 32 MiB
  unsigned short* W2T = (unsigned short*)(ws + (80l << 20));    // 32 MiB
  unsigned short* Hb  = (unsigned short*)(ws + (112l << 20));   // 64 MiB
  float* out = (float*)d_out;

  long slab = (long)FFN_DIM * D_DIM;
  transpose_kernel<<<dim3(D_DIM / 64, FFN_DIM / 64), 512, 0, stream>>>(w2, eidx, W2T);
  convert_kernel<<<2048, 256, 0, stream>>>(w1, eidx, slab, W1b, slab);
  convert_kernel<<<2048, 256, 0, stream>>>(v1, eidx, slab, V1b, slab);
  convert_kernel<<<2048, 256, 0, stream>>>(x,  eidx, 0,    Xb,  (long)T_DIM * D_DIM);
  gemm1_silu<<<1024, 512, 0, stream>>>(Xb, W1b, V1b, Hb);
  gemm2<<<256, 512, 0, stream>>>(Hb, W2T, out);
}